// Round 9
// baseline (154.569 us; speedup 1.0000x reference)
//
#include <hip/hip_runtime.h>
#include <hip/hip_bf16.h>

#define NN 100000   // nodes
#define H  256      // feature dim
#define NE 300000   // edges
#define KOUT 512    // y row length (u | v)
#define MT  782     // ceil(NN/128)

typedef __attribute__((ext_vector_type(8))) short short8;
typedef __attribute__((ext_vector_type(8))) unsigned short ushort8v;
typedef __attribute__((ext_vector_type(4))) float f32x4;

__device__ __forceinline__ unsigned short f2bf(float f) {
    unsigned int u = __float_as_uint(f);
    u += 0x7FFFu + ((u >> 16) & 1u);   // RNE
    return (unsigned short)(u >> 16);
}
__device__ __forceinline__ float bf2f(unsigned short h) {
    return __uint_as_float(((unsigned int)h) << 16);
}
// byte offset into a [rows][64] bf16 tile image (128B rows), XOR-swizzled
__device__ __forceinline__ int swz(int row, int coloff) {
    return row * 128 + (coloff ^ ((row & 7) << 4));
}
// async global->LDS, 16B per lane; LDS dest is wave-uniform base + lane*16
__device__ __forceinline__ void gload16(const void* g, void* l) {
    __builtin_amdgcn_global_load_lds((const __attribute__((address_space(1))) void*)g,
                                     (__attribute__((address_space(3))) void*)l,
                                     16, 0, 0);
}

// ---------------- W-prep: W1 (fp32 [512][256]) -> 16 pre-swizzled bf16 tiles.
// Tile t = nt*4 + ks. Image: [128 n][64 k] bf16, granule (n,kg) at byte swz(n, kg*16).
// Wcat[k][j]: j<256 -> W1[k][j]; j>=256 -> W1[k+256][j-256]; j = nt*128+n, k = ks*64+kz.
__global__ __launch_bounds__(256) void wprep(const float* __restrict__ W1,
                                             unsigned short* __restrict__ wsB) {
    int gtid = blockIdx.x * 256 + threadIdx.x;   // 16384 threads (64 blocks)
    int t  = gtid >> 10;          // 0..15
    int kg = (gtid >> 7) & 7;     // 8-k group
    int n  = gtid & 127;
    int nt = t >> 2, ks = t & 3;
    int krow0 = ks * 64 + kg * 8 + ((nt >= 2) ? 256 : 0);
    int col = (nt & 1) * 128 + n;
    const float* src = W1 + (size_t)krow0 * 256 + col;
    ushort8v p;
    #pragma unroll
    for (int i = 0; i < 8; ++i) p[i] = f2bf(src[(size_t)i * 256]);
    *(ushort8v*)((char*)(wsB + t * 8192) + swz(n, kg * 16)) = p;
}

// ---------------- X-prep v3: x (fp32) -> xb (bf16, plain row-major [NN][256]).
// Pure streaming convert: 32B in / 16B out per thread-iter, fully coalesced,
// every element read exactly once.
__global__ __launch_bounds__(256) void xprep3(const float* __restrict__ x,
                                              unsigned short* __restrict__ xb) {
    const int total = NN * H / 8;   // 3,200,000 granules of 8 floats
    for (int g = blockIdx.x * 256 + threadIdx.x; g < total; g += gridDim.x * 256) {
        const float* s = x + (size_t)g * 8;
        float4 v0 = *(const float4*)(s);
        float4 v1 = *(const float4*)(s + 4);
        ushort8v p;
        p[0]=f2bf(v0.x); p[1]=f2bf(v0.y); p[2]=f2bf(v0.z); p[3]=f2bf(v0.w);
        p[4]=f2bf(v1.x); p[5]=f2bf(v1.y); p[6]=f2bf(v1.z); p[7]=f2bf(v1.w);
        *(ushort8v*)(xb + (size_t)g * 8) = p;
    }
}

// ---------------- GEMM v9: A direct-from-global, B via gload_lds (dbuf 2x16KB).
// 128x128 tile, BK=64, 4 waves, 32KB LDS -> 4 blocks/CU (16 waves/CU).
// A-fragment per lane = xb[node][k..k+7] (16B, L2/L3-hot; lanes tile 64B lines).
// B pre-swizzled by wprep, staged linearly, read with swz. Swapped-operand MFMA
// -> transposed fragments -> packed 8B y stores.
__global__ __launch_bounds__(256, 4) void gemm_v9(const unsigned short* __restrict__ xb,
                                                  const unsigned short* __restrict__ wsB,
                                                  unsigned short* __restrict__ y) {
    __shared__ unsigned short Bl[2][8192];   // 2 x 16KB swizzled images
    const int tid = threadIdx.x;
    // bijective XCD swizzle: grid 3128 = 8 * 391; same-mt blocks co-XCD
    const int logical = ((int)blockIdx.x & 7) * ((int)gridDim.x >> 3) + ((int)blockIdx.x >> 3);
    const int mt = logical >> 2, nt = logical & 3;
    const int m0 = mt * 128, n0 = nt * 128;
    const int lane = tid & 63, wid = tid >> 6;
    const int wm = (wid >> 1) * 64, wn = (wid & 1) * 64;
    const int lr = lane & 15, lk = lane >> 4;

    // per-lane A row pointers (k-chunk lk*8 folded in); clamped for the tail tile
    const unsigned short* arow[4];
    #pragma unroll
    for (int mi = 0; mi < 4; ++mi) {
        int node = m0 + wm + mi * 16 + lr;
        if (node > NN - 1) node = NN - 1;
        arow[mi] = xb + (size_t)node * H + lk * 8;
    }
    const char* bsrc = (const char*)(wsB + nt * 4 * 8192) + wid * 4096 + lane * 16;

    f32x4 acc[4][4] = {};   // acc[ni][mi] — transposed (features x nodes)

    // prologue: stage B(0)
    #pragma unroll
    for (int i = 0; i < 4; ++i)
        gload16(bsrc + i * 1024, (char*)Bl[0] + wid * 4096 + i * 1024);
    __syncthreads();

    #pragma unroll
    for (int ks = 0; ks < 4; ++ks) {
        if (ks < 3) {   // stage next B first: flies under this step's compute
            #pragma unroll
            for (int i = 0; i < 4; ++i)
                gload16(bsrc + (ks + 1) * 16384 + i * 1024,
                        (char*)Bl[(ks + 1) & 1] + wid * 4096 + i * 1024);
        }
        const char* Bb = (const char*)Bl[ks & 1];
        #pragma unroll
        for (int kk = 0; kk < 64; kk += 32) {
            const int coloff = kk * 2 + lk * 16;
            short8 a[4], b[4];
            #pragma unroll
            for (int mi = 0; mi < 4; ++mi)
                a[mi] = *(const short8*)(arow[mi] + ks * 64 + kk);
            #pragma unroll
            for (int ni = 0; ni < 4; ++ni)
                b[ni] = *(const short8*)(Bb + swz(wn + ni * 16 + lr, coloff));
            #pragma unroll
            for (int ni = 0; ni < 4; ++ni)
                #pragma unroll
                for (int mi = 0; mi < 4; ++mi)
                    acc[ni][mi] = __builtin_amdgcn_mfma_f32_16x16x32_bf16(b[ni], a[mi], acc[ni][mi], 0, 0, 0);
        }
        if (ks < 3) __syncthreads();   // own stage landed + all waves done reading buf
    }
    // epilogue: lane holds 4 consecutive FEATURES (lk*4..+3) of node (lr)
    #pragma unroll
    for (int mi = 0; mi < 4; ++mi) {
        const int node = m0 + wm + mi * 16 + lr;
        if (node < NN) {
            #pragma unroll
            for (int ni = 0; ni < 4; ++ni) {
                const int feat = n0 + wn + ni * 16 + lk * 4;
                ushort4 u;
                u.x = f2bf(acc[ni][mi][0]);
                u.y = f2bf(acc[ni][mi][1]);
                u.z = f2bf(acc[ni][mi][2]);
                u.w = f2bf(acc[ni][mi][3]);
                *(ushort4*)(y + (size_t)node * KOUT + feat) = u;
            }
        }
    }
}

// ---------------- Phase 2: half-wave per edge, ushort8 gathers
__global__ __launch_bounds__(256) void edge_v2(const unsigned short* __restrict__ y,
                                               const int* __restrict__ ei,
                                               const float* __restrict__ b1,
                                               const float* __restrict__ W2,
                                               const float* __restrict__ b2,
                                               float* __restrict__ out) {
    const int tid = threadIdx.x;
    const int l32 = tid & 31;
    const int ghw = ((int)(blockIdx.x * blockDim.x) + tid) >> 5;
    const int nhw = ((int)(gridDim.x * blockDim.x)) >> 5;
    const int j = l32 * 8;
    const float4 b01 = *(const float4*)(b1 + j);
    const float4 b23 = *(const float4*)(b1 + j + 4);
    const float4 w01 = *(const float4*)(W2 + j);
    const float4 w23 = *(const float4*)(W2 + j + 4);
    const float bb = b2[0];
    #pragma unroll 2
    for (int e = ghw; e < NE; e += nhw) {
        int s = ei[e], d = ei[NE + e];
        s = s < 0 ? 0 : (s > NN - 1 ? NN - 1 : s);
        d = d < 0 ? 0 : (d > NN - 1 ? NN - 1 : d);
        ushort8v us = *(const ushort8v*)(y + (size_t)s * KOUT + j);
        ushort8v ud = *(const ushort8v*)(y + (size_t)d * KOUT + 256 + j);
        float acc;
        acc  = fmaxf(bf2f(us[0]) + bf2f(ud[0]) + b01.x, 0.f) * w01.x;
        acc += fmaxf(bf2f(us[1]) + bf2f(ud[1]) + b01.y, 0.f) * w01.y;
        acc += fmaxf(bf2f(us[2]) + bf2f(ud[2]) + b01.z, 0.f) * w01.z;
        acc += fmaxf(bf2f(us[3]) + bf2f(ud[3]) + b01.w, 0.f) * w01.w;
        acc += fmaxf(bf2f(us[4]) + bf2f(ud[4]) + b23.x, 0.f) * w23.x;
        acc += fmaxf(bf2f(us[5]) + bf2f(ud[5]) + b23.y, 0.f) * w23.y;
        acc += fmaxf(bf2f(us[6]) + bf2f(ud[6]) + b23.z, 0.f) * w23.z;
        acc += fmaxf(bf2f(us[7]) + bf2f(ud[7]) + b23.w, 0.f) * w23.w;
        #pragma unroll
        for (int off = 16; off > 0; off >>= 1) acc += __shfl_xor(acc, off, 64);
        if (l32 == 0) out[e] = acc + bb;
    }
}

// ---------------- Fallback (ws too small): fused wave-per-edge, fp32. Slow but correct.
__global__ __launch_bounds__(256) void fused_fallback(const float* __restrict__ x,
                                                      const int* __restrict__ ei,
                                                      const float* __restrict__ W1,
                                                      const float* __restrict__ b1,
                                                      const float* __restrict__ W2,
                                                      const float* __restrict__ b2,
                                                      float* __restrict__ out) {
    __shared__ float xsh[4][512];
    const int lane = threadIdx.x & 63;
    const int wl = threadIdx.x >> 6;
    const int gw = (blockIdx.x * blockDim.x + threadIdx.x) >> 6;
    const int nw = (gridDim.x * blockDim.x) >> 6;
    const int j = lane * 4;
    const float4 bv = *(const float4*)(b1 + j);
    const float4 wv = *(const float4*)(W2 + j);
    const float bb = b2[0];
    for (int e = gw; e < NE; e += nw) {
        int s = ei[e], d = ei[NE + e];
        s = min(max(s, 0), NN - 1);
        d = min(max(d, 0), NN - 1);
        __threadfence_block();
        #pragma unroll
        for (int i = 0; i < 4; ++i) {
            xsh[wl][i * 64 + lane]       = x[(size_t)s * H + i * 64 + lane];
            xsh[wl][256 + i * 64 + lane] = x[(size_t)d * H + i * 64 + lane];
        }
        __threadfence_block();
        float h0 = bv.x, h1 = bv.y, h2 = bv.z, h3 = bv.w;
        for (int k = 0; k < 256; ++k) {
            float xa = xsh[wl][k], xb2 = xsh[wl][256 + k];
            float4 wa = *(const float4*)(W1 + (size_t)k * 256 + j);
            float4 wb = *(const float4*)(W1 + (size_t)(k + 256) * 256 + j);
            h0 += xa * wa.x + xb2 * wb.x;
            h1 += xa * wa.y + xb2 * wb.y;
            h2 += xa * wa.z + xb2 * wb.z;
            h3 += xa * wa.w + xb2 * wb.w;
        }
        float acc = fmaxf(h0, 0.f) * wv.x + fmaxf(h1, 0.f) * wv.y +
                    fmaxf(h2, 0.f) * wv.z + fmaxf(h3, 0.f) * wv.w;
        #pragma unroll
        for (int off = 32; off > 0; off >>= 1) acc += __shfl_xor(acc, off, 64);
        if (lane == 0) out[e] = acc + bb;
    }
}

extern "C" void kernel_launch(void* const* d_in, const int* in_sizes, int n_in,
                              void* d_out, int out_size, void* d_ws, size_t ws_size,
                              hipStream_t stream) {
    const float* x  = (const float*)d_in[0];
    const int*   ei = (const int*)d_in[1];
    const float* W1 = (const float*)d_in[2];
    const float* b1 = (const float*)d_in[3];
    const float* W2 = (const float*)d_in[4];
    const float* b2 = (const float*)d_in[5];
    float* out = (float*)d_out;

    const size_t ybytes  = (size_t)NN * KOUT * sizeof(unsigned short);  // 102.4 MB
    const size_t xbbytes = (size_t)NN * H * sizeof(unsigned short);     // 51.2 MB
    const size_t wbytes  = 16 * 8192 * sizeof(unsigned short);          // 256 KB

    if (ws_size >= ybytes + xbbytes + wbytes) {
        unsigned short* yb  = (unsigned short*)d_ws;
        unsigned short* xbb = (unsigned short*)((char*)d_ws + ybytes);
        unsigned short* wb  = (unsigned short*)((char*)d_ws + ybytes + xbbytes);
        wprep<<<dim3(64), dim3(256), 0, stream>>>(W1, wb);
        xprep3<<<dim3(2048), dim3(256), 0, stream>>>(x, xbb);
        gemm_v9<<<dim3(MT * 4), dim3(256), 0, stream>>>(xbb, wb, yb);
        edge_v2<<<dim3(2048), dim3(256), 0, stream>>>(yb, ei, b1, W2, b2, out);
    } else {
        fused_fallback<<<dim3(2048), dim3(256), 0, stream>>>(x, ei, W1, b1, W2, b2, out);
    }
}

// Round 10
// 144.731 us; speedup vs baseline: 1.0680x; 1.0680x over previous
//
#include <hip/hip_runtime.h>
#include <hip/hip_bf16.h>

#define NN 100000   // nodes
#define H  256      // feature dim
#define NE 300000   // edges
#define KOUT 512    // y row length (u | v)
#define MT  782     // ceil(NN/128)

typedef __attribute__((ext_vector_type(8))) short short8;
typedef __attribute__((ext_vector_type(8))) unsigned short ushort8v;
typedef __attribute__((ext_vector_type(4))) float f32x4;

__device__ __forceinline__ unsigned short f2bf(float f) {
    unsigned int u = __float_as_uint(f);
    u += 0x7FFFu + ((u >> 16) & 1u);   // RNE
    return (unsigned short)(u >> 16);
}
__device__ __forceinline__ float bf2f(unsigned short h) {
    return __uint_as_float(((unsigned int)h) << 16);
}
// byte offset into a [rows][64] bf16 tile image (128B rows), XOR-swizzled
__device__ __forceinline__ int swz(int row, int coloff) {
    return row * 128 + (coloff ^ ((row & 7) << 4));
}
// async global->LDS, 16B per lane; LDS dest is wave-uniform base + lane*16
__device__ __forceinline__ void gload16(const void* g, void* l) {
    __builtin_amdgcn_global_load_lds((const __attribute__((address_space(1))) void*)g,
                                     (__attribute__((address_space(3))) void*)l,
                                     16, 0, 0);
}

// ---------------- W-prep: W1 (fp32 [512][256]) -> 16 pre-swizzled bf16 tiles.
// Tile t = nt*4 + ks. Image: [128 n][64 k] bf16, granule (n,kg) at byte swz(n, kg*16).
// Wcat[k][j]: j<256 -> W1[k][j]; j>=256 -> W1[k+256][j-256]; j = nt*128+n, k = ks*64+kz.
__global__ __launch_bounds__(256) void wprep(const float* __restrict__ W1,
                                             unsigned short* __restrict__ wsB) {
    int gtid = blockIdx.x * 256 + threadIdx.x;   // 16384 threads (64 blocks)
    int t  = gtid >> 10;          // 0..15
    int kg = (gtid >> 7) & 7;     // 8-k group
    int n  = gtid & 127;
    int nt = t >> 2, ks = t & 3;
    int krow0 = ks * 64 + kg * 8 + ((nt >= 2) ? 256 : 0);
    int col = (nt & 1) * 128 + n;
    const float* src = W1 + (size_t)krow0 * 256 + col;
    ushort8v p;
    #pragma unroll
    for (int i = 0; i < 8; ++i) p[i] = f2bf(src[(size_t)i * 256]);
    *(ushort8v*)((char*)(wsB + t * 8192) + swz(n, kg * 16)) = p;
}

// ---------------- GEMM v11: fused fp32->bf16 convert, full double-buffer.
// 128x128 tile, BK=64, 4 waves, LDS 64KB -> 2 blocks/CU.
// A: fp32 x loaded to regs (prefetched under MFMA), converted AFTER MFMA into
//    the other LDS buffer (never trapped between barriers). One barrier/step.
// B: global_load_lds from wprep's pre-swizzled tiles, double-buffered.
// Swapped-operand MFMA -> transposed fragments -> packed 8B y stores.
__global__ __launch_bounds__(256) void gemm_v11(const float* __restrict__ x,
                                                const unsigned short* __restrict__ wsB,
                                                unsigned short* __restrict__ y) {
    __shared__ unsigned short Al[2][8192];   // 2 x 16KB swizzled images
    __shared__ unsigned short Bl[2][8192];
    const int tid = threadIdx.x;
    // bijective XCD swizzle: grid 3128 = 8 * 391; same-mt blocks co-XCD
    const int logical = ((int)blockIdx.x & 7) * ((int)gridDim.x >> 3) + ((int)blockIdx.x >> 3);
    const int mt = logical >> 2, nt = logical & 3;
    const int m0 = mt * 128, n0 = nt * 128;
    const int lane = tid & 63, wid = tid >> 6;
    const int wm = (wid >> 1) * 64, wn = (wid & 1) * 64;
    const int lr = lane & 15, lk = lane >> 4;

    // A staging: thread -> (row ar, half hg); 32 consecutive floats (128B) per thread
    const int ar = tid >> 1, hg = tid & 1;
    int node_s = m0 + ar; if (node_s > NN - 1) node_s = NN - 1;
    const float* xs = x + (size_t)node_s * H + hg * 32;

    const char* bsrc = (const char*)(wsB + nt * 4 * 8192) + wid * 4096 + lane * 16;

    float4 pA[8];
    auto loadA = [&](int ks) {
        const float* s = xs + ks * 64;
        #pragma unroll
        for (int q = 0; q < 8; ++q) pA[q] = *(const float4*)(s + q * 4);
    };
    auto convA = [&](int buf) {
        char* ab = (char*)Al[buf];
        #pragma unroll
        for (int q = 0; q < 4; ++q) {
            ushort8v p;
            p[0] = f2bf(pA[2*q].x);   p[1] = f2bf(pA[2*q].y);
            p[2] = f2bf(pA[2*q].z);   p[3] = f2bf(pA[2*q].w);
            p[4] = f2bf(pA[2*q+1].x); p[5] = f2bf(pA[2*q+1].y);
            p[6] = f2bf(pA[2*q+1].z); p[7] = f2bf(pA[2*q+1].w);
            *(ushort8v*)(ab + swz(ar, hg * 64 + q * 16)) = p;
        }
    };

    f32x4 acc[4][4] = {};   // acc[ni][mi] — transposed (features x nodes)

    // prologue: A(0) convert + B(0) stage into buf 0
    loadA(0);
    #pragma unroll
    for (int i = 0; i < 4; ++i)
        gload16(bsrc + i * 1024, (char*)Bl[0] + wid * 4096 + i * 1024);
    convA(0);
    __syncthreads();   // drains vmcnt (B) + lgkm (A writes)

    #pragma unroll
    for (int ks = 0; ks < 4; ++ks) {
        if (ks < 3) {
            loadA(ks + 1);     // fp32 regs: latency flies under MFMA below
            #pragma unroll
            for (int i = 0; i < 4; ++i)
                gload16(bsrc + (ks + 1) * 16384 + i * 1024,
                        (char*)Bl[(ks + 1) & 1] + wid * 4096 + i * 1024);
        }
        const char* Ab = (const char*)Al[ks & 1];
        const char* Bb = (const char*)Bl[ks & 1];
        #pragma unroll
        for (int kk = 0; kk < 64; kk += 32) {
            const int coloff = kk * 2 + lk * 16;
            short8 a[4], b[4];
            #pragma unroll
            for (int mi = 0; mi < 4; ++mi)
                a[mi] = *(const short8*)(Ab + swz(wm + mi * 16 + lr, coloff));
            #pragma unroll
            for (int ni = 0; ni < 4; ++ni)
                b[ni] = *(const short8*)(Bb + swz(wn + ni * 16 + lr, coloff));
            #pragma unroll
            for (int ni = 0; ni < 4; ++ni)
                #pragma unroll
                for (int mi = 0; mi < 4; ++mi)
                    acc[ni][mi] = __builtin_amdgcn_mfma_f32_16x16x32_bf16(b[ni], a[mi], acc[ni][mi], 0, 0, 0);
        }
        if (ks < 3) {
            convA((ks + 1) & 1);   // convert AFTER MFMA into free buffer
            __syncthreads();        // B(ks+1) landed + A(ks+1) written + reads done
        }
    }
    // epilogue: lane holds 4 consecutive FEATURES (lk*4..+3) of node (lr)
    #pragma unroll
    for (int mi = 0; mi < 4; ++mi) {
        const int node = m0 + wm + mi * 16 + lr;
        if (node < NN) {
            #pragma unroll
            for (int ni = 0; ni < 4; ++ni) {
                const int feat = n0 + wn + ni * 16 + lk * 4;
                ushort4 u;
                u.x = f2bf(acc[ni][mi][0]);
                u.y = f2bf(acc[ni][mi][1]);
                u.z = f2bf(acc[ni][mi][2]);
                u.w = f2bf(acc[ni][mi][3]);
                *(ushort4*)(y + (size_t)node * KOUT + feat) = u;
            }
        }
    }
}

// ---------------- Phase 2: half-wave per edge, ushort8 gathers
__global__ __launch_bounds__(256) void edge_v2(const unsigned short* __restrict__ y,
                                               const int* __restrict__ ei,
                                               const float* __restrict__ b1,
                                               const float* __restrict__ W2,
                                               const float* __restrict__ b2,
                                               float* __restrict__ out) {
    const int tid = threadIdx.x;
    const int l32 = tid & 31;
    const int ghw = ((int)(blockIdx.x * blockDim.x) + tid) >> 5;
    const int nhw = ((int)(gridDim.x * blockDim.x)) >> 5;
    const int j = l32 * 8;
    const float4 b01 = *(const float4*)(b1 + j);
    const float4 b23 = *(const float4*)(b1 + j + 4);
    const float4 w01 = *(const float4*)(W2 + j);
    const float4 w23 = *(const float4*)(W2 + j + 4);
    const float bb = b2[0];
    #pragma unroll 2
    for (int e = ghw; e < NE; e += nhw) {
        int s = ei[e], d = ei[NE + e];
        s = s < 0 ? 0 : (s > NN - 1 ? NN - 1 : s);
        d = d < 0 ? 0 : (d > NN - 1 ? NN - 1 : d);
        ushort8v us = *(const ushort8v*)(y + (size_t)s * KOUT + j);
        ushort8v ud = *(const ushort8v*)(y + (size_t)d * KOUT + 256 + j);
        float acc;
        acc  = fmaxf(bf2f(us[0]) + bf2f(ud[0]) + b01.x, 0.f) * w01.x;
        acc += fmaxf(bf2f(us[1]) + bf2f(ud[1]) + b01.y, 0.f) * w01.y;
        acc += fmaxf(bf2f(us[2]) + bf2f(ud[2]) + b01.z, 0.f) * w01.z;
        acc += fmaxf(bf2f(us[3]) + bf2f(ud[3]) + b01.w, 0.f) * w01.w;
        acc += fmaxf(bf2f(us[4]) + bf2f(ud[4]) + b23.x, 0.f) * w23.x;
        acc += fmaxf(bf2f(us[5]) + bf2f(ud[5]) + b23.y, 0.f) * w23.y;
        acc += fmaxf(bf2f(us[6]) + bf2f(ud[6]) + b23.z, 0.f) * w23.z;
        acc += fmaxf(bf2f(us[7]) + bf2f(ud[7]) + b23.w, 0.f) * w23.w;
        #pragma unroll
        for (int off = 16; off > 0; off >>= 1) acc += __shfl_xor(acc, off, 64);
        if (l32 == 0) out[e] = acc + bb;
    }
}

// ---------------- Fallback (ws too small): fused wave-per-edge, fp32. Slow but correct.
__global__ __launch_bounds__(256) void fused_fallback(const float* __restrict__ x,
                                                      const int* __restrict__ ei,
                                                      const float* __restrict__ W1,
                                                      const float* __restrict__ b1,
                                                      const float* __restrict__ W2,
                                                      const float* __restrict__ b2,
                                                      float* __restrict__ out) {
    __shared__ float xsh[4][512];
    const int lane = threadIdx.x & 63;
    const int wl = threadIdx.x >> 6;
    const int gw = (blockIdx.x * blockDim.x + threadIdx.x) >> 6;
    const int nw = (gridDim.x * blockDim.x) >> 6;
    const int j = lane * 4;
    const float4 bv = *(const float4*)(b1 + j);
    const float4 wv = *(const float4*)(W2 + j);
    const float bb = b2[0];
    for (int e = gw; e < NE; e += nw) {
        int s = ei[e], d = ei[NE + e];
        s = min(max(s, 0), NN - 1);
        d = min(max(d, 0), NN - 1);
        __threadfence_block();
        #pragma unroll
        for (int i = 0; i < 4; ++i) {
            xsh[wl][i * 64 + lane]       = x[(size_t)s * H + i * 64 + lane];
            xsh[wl][256 + i * 64 + lane] = x[(size_t)d * H + i * 64 + lane];
        }
        __threadfence_block();
        float h0 = bv.x, h1 = bv.y, h2 = bv.z, h3 = bv.w;
        for (int k = 0; k < 256; ++k) {
            float xa = xsh[wl][k], xb2 = xsh[wl][256 + k];
            float4 wa = *(const float4*)(W1 + (size_t)k * 256 + j);
            float4 wb = *(const float4*)(W1 + (size_t)(k + 256) * 256 + j);
            h0 += xa * wa.x + xb2 * wb.x;
            h1 += xa * wa.y + xb2 * wb.y;
            h2 += xa * wa.z + xb2 * wb.z;
            h3 += xa * wa.w + xb2 * wb.w;
        }
        float acc = fmaxf(h0, 0.f) * wv.x + fmaxf(h1, 0.f) * wv.y +
                    fmaxf(h2, 0.f) * wv.z + fmaxf(h3, 0.f) * wv.w;
        #pragma unroll
        for (int off = 32; off > 0; off >>= 1) acc += __shfl_xor(acc, off, 64);
        if (lane == 0) out[e] = acc + bb;
    }
}

extern "C" void kernel_launch(void* const* d_in, const int* in_sizes, int n_in,
                              void* d_out, int out_size, void* d_ws, size_t ws_size,
                              hipStream_t stream) {
    const float* x  = (const float*)d_in[0];
    const int*   ei = (const int*)d_in[1];
    const float* W1 = (const float*)d_in[2];
    const float* b1 = (const float*)d_in[3];
    const float* W2 = (const float*)d_in[4];
    const float* b2 = (const float*)d_in[5];
    float* out = (float*)d_out;

    const size_t ybytes = (size_t)NN * KOUT * sizeof(unsigned short);  // 102.4 MB
    const size_t wbytes = 16 * 8192 * sizeof(unsigned short);          // 256 KB

    if (ws_size >= ybytes + wbytes) {
        unsigned short* yb = (unsigned short*)d_ws;
        unsigned short* wb = (unsigned short*)((char*)d_ws + ybytes);
        wprep<<<dim3(64), dim3(256), 0, stream>>>(W1, wb);
        gemm_v11<<<dim3(MT * 4), dim3(256), 0, stream>>>(x, wb, yb);
        edge_v2<<<dim3(2048), dim3(256), 0, stream>>>(yb, ei, b1, W2, b2, out);
    } else {
        fused_fallback<<<dim3(2048), dim3(256), 0, stream>>>(x, ei, W1, b1, W2, b2, out);
    }
}